// Round 3
// baseline (1335.837 us; speedup 1.0000x reference)
//
#include <hip/hip_runtime.h>
#include <hip/hip_bf16.h>

#define NB 2048      // batches
#define NP 32        // particles per batch
#define ND 6         // action dim
#define NOBS 17      // obs dim
#define NH 256       // hidden
#define NSTEPS 10
#define C_LR 0.1f
#define C_LIM 1.0f
#define C_LOGNP1 3.4965075614664802f   // float32(log(33))

typedef __bf16 bf16x8 __attribute__((ext_vector_type(8)));
typedef float  f32x4  __attribute__((ext_vector_type(4)));

#define MFMA(a, b, c) __builtin_amdgcn_mfma_f32_16x16x32_bf16(a, b, c, 0, 0, 0)

// fp32 -> bf16 bits, round-to-nearest-even (finite inputs)
static __device__ __forceinline__ unsigned short f2bf(float f) {
    union { float f; unsigned u; } c; c.f = f;
    const unsigned r = c.u + 0x7fffu + ((c.u >> 16) & 1u);
    return (unsigned short)(r >> 16);
}

// Radix scan pass (wave 0 only): pick bucket containing rank selRank in hist[b],
// fold bucket id into selP byte b, reduce selRank.
static __device__ __forceinline__ void radix_scan(const int* __restrict__ hist,
                                                  unsigned* selP, int* selRank,
                                                  int t, int b) {
    if (t < 64) {
        const int4 hq = *(const int4*)&hist[4 * t];
        const int tot = hq.x + hq.y + hq.z + hq.w;
        int incl = tot;
#pragma unroll
        for (int off = 1; off < 64; off <<= 1) {
            const int nbr = __shfl_up(incl, off);
            if (t >= off) incl += nbr;
        }
        const int base = incl - tot;
        const int r = *selRank;            // read by all lanes before any write
        if (r >= base && r < incl) {       // exactly one lane
            int nb = base, bin = 0;
            if (r >= nb + hq.x) { nb += hq.x; bin = 1;
                if (r >= nb + hq.y) { nb += hq.y; bin = 2;
                    if (r >= nb + hq.z) { nb += hq.z; bin = 3; } } }
            *selP |= (unsigned)(4 * t + bin) << (8 * b);
            *selRank = r - nb;
        }
    }
}

// ---------------------------------------------------------------------------
// Prep: B-fragment-swizzled bf16 copies of W2, W2^T, W1x^T in d_ws (unchanged).
// ---------------------------------------------------------------------------
__global__ void prep_swizzle(const float* __restrict__ W1, const float* __restrict__ W2,
                             unsigned short* __restrict__ ws) {
    const int g = blockIdx.x * 256 + threadIdx.x;
    unsigned short v[8];
    if (g < 8192) {
        const int l = g & 63, fid = g >> 6;
        const int kt = fid >> 4, nt = fid & 15;
        const int row0 = kt * 32 + (l >> 4) * 8;
        const int col  = nt * 16 + (l & 15);
#pragma unroll
        for (int j = 0; j < 8; ++j) v[j] = f2bf(W2[(row0 + j) * NH + col]);
        ushort4* dst = (ushort4*)(ws + (size_t)g * 8);
        dst[0] = make_ushort4(v[0], v[1], v[2], v[3]);
        dst[1] = make_ushort4(v[4], v[5], v[6], v[7]);
    } else if (g < 16384) {
        const int e = g - 8192;
        const int l = e & 63, fid = e >> 6;
        const int kt = fid >> 4, nt = fid & 15;
        const int row  = nt * 16 + (l & 15);        // W2^T[k][n] = W2[n][k]
        const int col0 = kt * 32 + (l >> 4) * 8;
#pragma unroll
        for (int j = 0; j < 8; ++j) v[j] = f2bf(W2[row * NH + col0 + j]);
        ushort4* dst = (ushort4*)(ws + 65536 + (size_t)e * 8);
        dst[0] = make_ushort4(v[0], v[1], v[2], v[3]);
        dst[1] = make_ushort4(v[4], v[5], v[6], v[7]);
    } else if (g < 16896) {
        const int e = g - 16384;
        const int l = e & 63, kt = e >> 6;
        const int n  = l & 15;
        const int k0 = kt * 32 + (l >> 4) * 8;
#pragma unroll
        for (int j = 0; j < 8; ++j)
            v[j] = (n < ND) ? f2bf(W1[(NOBS + n) * NH + k0 + j]) : (unsigned short)0;
        ushort4* dst = (ushort4*)(ws + 131072 + (size_t)e * 8);
        dst[0] = make_ushort4(v[0], v[1], v[2], v[3]);
        dst[1] = make_ushort4(v[4], v[5], v[6], v[7]);
    }
}

// ---------------------------------------------------------------------------
// Main kernel: one WG per batch, 256 threads = 4 waves.
// ---------------------------------------------------------------------------
__global__ __launch_bounds__(256, 3)
void svgd_kernel(const float* __restrict__ obs, const float* __restrict__ a_in,
                 const float* __restrict__ W1, const float* __restrict__ b1,
                 const float* __restrict__ W2, const float* __restrict__ b2,
                 const float* __restrict__ W3, const unsigned short* __restrict__ ws,
                 float* __restrict__ out)
{
    __shared__ __attribute__((aligned(16))) unsigned short hA[NP * NH]; // 16KB h1 / masked dh1
    __shared__ __attribute__((aligned(16))) unsigned short dA[NP * NH]; // 16KB dh2
    __shared__ __attribute__((aligned(16))) float dsp_[NP * 33];        // 4.2KB dist_sq padded (obs staging at init)
    __shared__ __attribute__((aligned(16))) int hist_[4 * 256];         // 4KB radix histograms
    __shared__ float sc_[NP * 9];       // score, stride 9 (conflict-free)
    __shared__ float Xs[NP * 9];        // X, stride 9
    __shared__ float b2s[NH], W3s[NH];  // 2KB
    __shared__ float logp_s[NP];
    __shared__ unsigned selP;
    __shared__ int selRank;

    const int t    = threadIdx.x;
    const int b    = blockIdx.x;
    const int lane = t & 63;
    const int w4   = (t >> 6) * 4;      // this wave's first nt
    const int quad = lane >> 4;
    const int jx = t & 63;              // phase-1 col group
    const int sy = t >> 6;
    const int j0 = jx * 4;
    const int s0 = sy * 8;

    const unsigned short* gW2f = ws;
    const unsigned short* gW2b = ws + 65536;
    const unsigned short* gW1p = ws + 131072;

    // ---- init ----
    const float* obs_g = obs + b * (NP * NOBS);
    for (int p = t; p < NP * NOBS; p += 256) dsp_[p] = obs_g[p];
    const float* a_g = a_in + b * (NP * ND);
    if (t < NP * ND) { int s = t / ND; int d = t - s * ND; Xs[s * 9 + d] = a_g[t]; }
    if (t < NP) logp_s[t] = 0.0f;
    b2s[t] = b2[t];
    W3s[t] = W3[t];
    hist_[t] = 0; hist_[256 + t] = 0; hist_[512 + t] = 0; hist_[768 + t] = 0;
    if (t == 0) { selP = 0u; selRank = 239; }

    // pair-index table (step-invariant): p-th (i<j) pair -> padded addr i*33+j
    int pa0, pa1;
    {
        int rem = t, i0 = 0;
        while (rem >= 31 - i0) { rem -= 31 - i0; ++i0; }
        pa0 = i0 * 33 + i0 + 1 + rem;
        pa1 = pa0;
        if (t < 240) {
            int rem1 = t + 256, i1 = 0;
            while (rem1 >= 31 - i1) { rem1 -= 31 - i1; ++i1; }
            pa1 = i1 * 33 + i1 + 1 + rem1;
        }
    }
    __syncthreads();

    // ---- step-invariant register preloads ----
    float W1xr[ND][4];
#pragma unroll
    for (int d = 0; d < ND; ++d) {
        const float4 w = *(const float4*)(W1 + (NOBS + d) * NH + j0);
        W1xr[d][0] = w.x; W1xr[d][1] = w.y; W1xr[d][2] = w.z; W1xr[d][3] = w.w;
    }
    // c1 = obs @ W1[:17] + b1  (step-invariant)
    float c1[8][4];
    {
        const float4 b1r = *(const float4*)(b1 + j0);
#pragma unroll
        for (int ss = 0; ss < 8; ++ss) {
            c1[ss][0] = b1r.x; c1[ss][1] = b1r.y; c1[ss][2] = b1r.z; c1[ss][3] = b1r.w;
        }
        for (int k = 0; k < NOBS; ++k) {
            const float4 w = *(const float4*)(W1 + k * NH + j0);
#pragma unroll
            for (int ss = 0; ss < 8; ++ss) {
                const float o = dsp_[(s0 + ss) * NOBS + k];
                c1[ss][0] += o * w.x; c1[ss][1] += o * w.y;
                c1[ss][2] += o * w.z; c1[ss][3] += o * w.w;
            }
        }
    }
    __syncthreads();  // dsp_ free now

    for (int step = 0; step < NSTEPS; ++step) {
        // ---- P1: h1 = relu(c1 + X @ W1x) -> hA bf16 (A-layout) ----
#pragma unroll
        for (int ss = 0; ss < 8; ++ss) {
            const int s = s0 + ss;
            float h0 = c1[ss][0], h1v = c1[ss][1], h2v = c1[ss][2], h3 = c1[ss][3];
#pragma unroll
            for (int d = 0; d < ND; ++d) {
                const float xv = Xs[s * 9 + d];
                h0 += xv * W1xr[d][0]; h1v += xv * W1xr[d][1];
                h2v += xv * W1xr[d][2]; h3 += xv * W1xr[d][3];
            }
            const int fid = (j0 >> 5) * 2 + (s >> 4);
            const int lp  = ((j0 >> 3) & 3) * 16 + (s & 15);
            *(ushort4*)&hA[fid * 512 + lp * 8 + (j0 & 7)] =
                make_ushort4(f2bf(fmaxf(h0, 0.f)), f2bf(fmaxf(h1v, 0.f)),
                             f2bf(fmaxf(h2v, 0.f)), f2bf(fmaxf(h3, 0.f)));
        }
        // ---- P6 (fused): dist_sq -> dsp_ (stride 33) ----
#pragma unroll
        for (int m = 0; m < 4; ++m) {
            const int p = t + 256 * m;
            const int i = p >> 5, j = p & 31;
            float s = 0.0f;
#pragma unroll
            for (int d = 0; d < ND; ++d) {
                const float df = Xs[i * 9 + d] - Xs[j * 9 + d];
                s += df * df;
            }
            dsp_[i * 33 + j] = s;
        }
        __syncthreads();  // S1

        // radix candidates (positive floats: bit pattern is order-isomorphic)
        const unsigned u0 = __float_as_uint(dsp_[pa0]);
        const bool has1 = (t < 240);
        const unsigned u1 = has1 ? __float_as_uint(dsp_[pa1]) : 0u;

        // ---- P2: fwd GEMM h2_pre = h1 @ W2 (MFMA) + radix acc pass 3 ----
        f32x4 acc[2][4];
        const f32x4 zv = {0.f, 0.f, 0.f, 0.f};
#pragma unroll
        for (int mt = 0; mt < 2; ++mt)
#pragma unroll
            for (int q = 0; q < 4; ++q) acc[mt][q] = zv;
#pragma unroll 2
        for (int kt = 0; kt < 8; ++kt) {
            const bf16x8 a0 = *(const bf16x8*)&hA[(kt * 2 + 0) * 512 + lane * 8];
            const bf16x8 a1 = *(const bf16x8*)&hA[(kt * 2 + 1) * 512 + lane * 8];
#pragma unroll
            for (int q = 0; q < 4; ++q) {
                const bf16x8 bf = *(const bf16x8*)(gW2f + ((kt * 16 + w4 + q) * 64 + lane) * 8);
                acc[0][q] = MFMA(a0, bf, acc[0][q]);
                acc[1][q] = MFMA(a1, bf, acc[1][q]);
            }
        }
        atomicAdd(&hist_[3 * 256 + (u0 >> 24)], 1);
        if (has1) atomicAdd(&hist_[3 * 256 + (u1 >> 24)], 1);
        // epilogue: dh2 = (h2_pre + b2 > 0) ? W3 : 0 -> dA
#pragma unroll
        for (int q = 0; q < 4; ++q) {
            const int n = (w4 + q) * 16 + (lane & 15);
            const float b2v = b2s[n];
            const unsigned short w3v = f2bf(W3s[n]);
            const int base = ((n >> 5) * 2) * 512 + (((n >> 3) & 3) * 16) * 8 + (n & 7);
#pragma unroll
            for (int mt = 0; mt < 2; ++mt)
#pragma unroll
                for (int reg = 0; reg < 4; ++reg) {
                    const float hp = acc[mt][q][reg] + b2v;
                    dA[base + mt * 512 + (quad * 4 + reg) * 8] =
                        (hp > 0.f) ? w3v : (unsigned short)0;
                }
        }
        __syncthreads();  // S2

        // ---- P3: bwd GEMM dh1 = dh2 @ W2^T (MFMA) + radix scan pass 3 ----
        f32x4 acc2[2][4];
#pragma unroll
        for (int mt = 0; mt < 2; ++mt)
#pragma unroll
            for (int q = 0; q < 4; ++q) acc2[mt][q] = zv;
#pragma unroll 2
        for (int kt = 0; kt < 8; ++kt) {
            const bf16x8 a0 = *(const bf16x8*)&dA[(kt * 2 + 0) * 512 + lane * 8];
            const bf16x8 a1 = *(const bf16x8*)&dA[(kt * 2 + 1) * 512 + lane * 8];
#pragma unroll
            for (int q = 0; q < 4; ++q) {
                const bf16x8 bf = *(const bf16x8*)(gW2b + ((kt * 16 + w4 + q) * 64 + lane) * 8);
                acc2[0][q] = MFMA(a0, bf, acc2[0][q]);
                acc2[1][q] = MFMA(a1, bf, acc2[1][q]);
            }
        }
        radix_scan(&hist_[3 * 256], &selP, &selRank, t, 3);
        // ---- P4: hA <- dh1 * mask, in place (wave-disjoint columns) ----
#pragma unroll
        for (int q = 0; q < 4; ++q) {
            const int c = (w4 + q) * 16 + (lane & 15);
            const int base = ((c >> 5) * 2) * 512 + (((c >> 3) & 3) * 16) * 8 + (c & 7);
#pragma unroll
            for (int mt = 0; mt < 2; ++mt)
#pragma unroll
                for (int reg = 0; reg < 4; ++reg) {
                    const int idx = base + mt * 512 + (quad * 4 + reg) * 8;
                    const unsigned short hu = hA[idx];
                    hA[idx] = hu ? f2bf(acc2[mt][q][reg]) : (unsigned short)0;
                }
        }
        __syncthreads();  // S3

        // ---- P5: score GEMM s = (dh1*mask) @ W1x^T + radix acc pass 2 ----
        {
            const unsigned sp = selP;
            if ((u0 >> 24) == (sp >> 24)) atomicAdd(&hist_[2 * 256 + ((u0 >> 16) & 255)], 1);
            if (has1 && (u1 >> 24) == (sp >> 24)) atomicAdd(&hist_[2 * 256 + ((u1 >> 16) & 255)], 1);
            f32x4 sa0 = zv, sa1 = zv;
#pragma unroll
            for (int kt = 0; kt < 8; ++kt) {
                const bf16x8 a0 = *(const bf16x8*)&hA[(kt * 2 + 0) * 512 + lane * 8];
                const bf16x8 a1 = *(const bf16x8*)&hA[(kt * 2 + 1) * 512 + lane * 8];
                const bf16x8 bw = *(const bf16x8*)(gW1p + (kt * 64 + lane) * 8);
                sa0 = MFMA(a0, bw, sa0);
                sa1 = MFMA(a1, bw, sa1);
            }
            if (t < 64) {
                const int col = lane & 15;
                if (col < ND) {
#pragma unroll
                    for (int reg = 0; reg < 4; ++reg) {
                        sc_[(quad * 4 + reg) * 9 + col]      = sa0[reg];
                        sc_[(16 + quad * 4 + reg) * 9 + col] = sa1[reg];
                    }
                }
            }
        }
        __syncthreads();  // S5

        radix_scan(&hist_[2 * 256], &selP, &selRank, t, 2);
        __syncthreads();  // B6
        {
            const unsigned sp = selP;
            if ((u0 >> 16) == (sp >> 16)) atomicAdd(&hist_[1 * 256 + ((u0 >> 8) & 255)], 1);
            if (has1 && (u1 >> 16) == (sp >> 16)) atomicAdd(&hist_[1 * 256 + ((u1 >> 8) & 255)], 1);
        }
        __syncthreads();  // B7
        radix_scan(&hist_[1 * 256], &selP, &selRank, t, 1);
        __syncthreads();  // B8
        {
            const unsigned sp = selP;
            if ((u0 >> 8) == (sp >> 8)) atomicAdd(&hist_[0 * 256 + (u0 & 255)], 1);
            if (has1 && (u1 >> 8) == (sp >> 8)) atomicAdd(&hist_[0 * 256 + (u1 & 255)], 1);
        }
        __syncthreads();  // B9
        radix_scan(&hist_[0 * 256], &selP, &selRank, t, 0);
        __syncthreads();  // B10

        const float med = __uint_as_float(selP);   // exact rank-511-of-1024 median
        const float gam = 1.0f / (1e-8f + med / C_LOGNP1);

        // ---- stage A: per-(i, jg) partials over 4 j's + 8-lane butterfly ----
        {
            const int ia = t >> 3, jg = t & 7;
            float xi[ND];
#pragma unroll
            for (int d = 0; d < ND; ++d) xi[d] = Xs[ia * 9 + d];
            float w[8] = {0, 0, 0, 0, 0, 0, 0, 0};
#pragma unroll
            for (int jj = 0; jj < 4; ++jj) {
                const int j = jg * 4 + jj;
                const float dsv = dsp_[ia * 33 + j];
                const float kap = __expf(-gam * dsv);
                const float tg = 2.0f * gam * kap;
                float dot = 0.0f;
#pragma unroll
                for (int d = 0; d < ND; ++d) {
                    const float df = xi[d] - Xs[j * 9 + d];
                    const float sj = sc_[j * 9 + d];
                    w[d] += kap * sj + tg * df;   // phi numerator
                    dot += df * sj;
                }
                w[6] -= tg * dot;                 // line_4 partial
                w[7] += tg * dsv - 6.0f * kap;    // line_5 partial (pre -2*gamma)
            }
#pragma unroll
            for (int off = 1; off < 8; off <<= 1)
#pragma unroll
                for (int c = 0; c < 8; ++c) w[c] += __shfl_xor(w[c], off);
            __syncthreads();  // B11: all Xs/dsp_/sc_ reads done

            // commit: X update (lanes jg<6), logp (jg==6); reset radix state
            if (jg < 6) {
                float x = Xs[ia * 9 + jg] + C_LR * (w[jg] * (1.0f / 32.0f));
                Xs[ia * 9 + jg] = fminf(fmaxf(x, -C_LIM), C_LIM);
            } else if (jg == 6) {
                logp_s[ia] -= C_LR * (w[6] * (1.0f / 32.0f)
                                      - 2.0f * gam * (w[7] * (1.0f / 32.0f)));
            }
            hist_[t] = 0; hist_[256 + t] = 0; hist_[512 + t] = 0; hist_[768 + t] = 0;
            if (t == 0) { selP = 0u; selRank = 239; }
        }
        __syncthreads();  // B12
    }

    // ---- output: a (B*N, D) then logp (B, N) ----
    if (t < NP * ND) out[b * (NP * ND) + t] = Xs[(t / ND) * 9 + (t % ND)];
    if (t < NP) out[NB * NP * ND + b * NP + t] = logp_s[t];
}

extern "C" void kernel_launch(void* const* d_in, const int* in_sizes, int n_in,
                              void* d_out, int out_size, void* d_ws, size_t ws_size,
                              hipStream_t stream) {
    const float* obs = (const float*)d_in[0];
    const float* a   = (const float*)d_in[1];
    const float* W1  = (const float*)d_in[2];
    const float* b1  = (const float*)d_in[3];
    const float* W2  = (const float*)d_in[4];
    const float* b2  = (const float*)d_in[5];
    const float* W3  = (const float*)d_in[6];
    // d_in[7] = b3: unused (constant offset drops out of grad; q-values never output)
    unsigned short* wsu = (unsigned short*)d_ws;   // needs 270336 bytes
    float* out = (float*)d_out;

    prep_swizzle<<<66, 256, 0, stream>>>(W1, W2, wsu);
    svgd_kernel<<<NB, 256, 0, stream>>>(obs, a, W1, b1, W2, b2, W3, wsu, out);
}

// Round 4
// 928.967 us; speedup vs baseline: 1.4380x; 1.4380x over previous
//
#include <hip/hip_runtime.h>
#include <hip/hip_bf16.h>

#define NB 2048      // batches
#define NP 32        // particles per batch
#define ND 6         // action dim
#define NOBS 17      // obs dim
#define NH 256       // hidden
#define NSTEPS 10
#define C_LR 0.1f
#define C_LIM 1.0f
#define C_LOGNP1 3.4965075614664802f   // float32(log(33))

typedef __bf16 bf16x8 __attribute__((ext_vector_type(8)));
typedef float  f32x4  __attribute__((ext_vector_type(4)));

#define MFMA(a, b, c) __builtin_amdgcn_mfma_f32_16x16x32_bf16(a, b, c, 0, 0, 0)

// fp32 -> bf16 bits, round-to-nearest-even (finite inputs)
static __device__ __forceinline__ unsigned short f2bf(float f) {
    union { float f; unsigned u; } c; c.f = f;
    const unsigned r = c.u + 0x7fffu + ((c.u >> 16) & 1u);
    return (unsigned short)(r >> 16);
}

// ---------------------------------------------------------------------------
// Prep: B-fragment-swizzled bf16 copies of W2, W2^T, W1x^T in d_ws (unchanged).
// Fragment (kt,nt): lane l, elem j -> B[kt*32 + (l>>4)*8 + j][nt*16 + (l&15)].
// ---------------------------------------------------------------------------
__global__ void prep_swizzle(const float* __restrict__ W1, const float* __restrict__ W2,
                             unsigned short* __restrict__ ws) {
    const int g = blockIdx.x * 256 + threadIdx.x;
    unsigned short v[8];
    if (g < 8192) {
        const int l = g & 63, fid = g >> 6;
        const int kt = fid >> 4, nt = fid & 15;
        const int row0 = kt * 32 + (l >> 4) * 8;
        const int col  = nt * 16 + (l & 15);
#pragma unroll
        for (int j = 0; j < 8; ++j) v[j] = f2bf(W2[(row0 + j) * NH + col]);
        ushort4* dst = (ushort4*)(ws + (size_t)g * 8);
        dst[0] = make_ushort4(v[0], v[1], v[2], v[3]);
        dst[1] = make_ushort4(v[4], v[5], v[6], v[7]);
    } else if (g < 16384) {
        const int e = g - 8192;
        const int l = e & 63, fid = e >> 6;
        const int kt = fid >> 4, nt = fid & 15;
        const int row  = nt * 16 + (l & 15);        // W2^T[k][n] = W2[n][k]
        const int col0 = kt * 32 + (l >> 4) * 8;
#pragma unroll
        for (int j = 0; j < 8; ++j) v[j] = f2bf(W2[row * NH + col0 + j]);
        ushort4* dst = (ushort4*)(ws + 65536 + (size_t)e * 8);
        dst[0] = make_ushort4(v[0], v[1], v[2], v[3]);
        dst[1] = make_ushort4(v[4], v[5], v[6], v[7]);
    } else if (g < 16896) {
        const int e = g - 16384;
        const int l = e & 63, kt = e >> 6;
        const int n  = l & 15;
        const int k0 = kt * 32 + (l >> 4) * 8;
#pragma unroll
        for (int j = 0; j < 8; ++j)
            v[j] = (n < ND) ? f2bf(W1[(NOBS + n) * NH + k0 + j]) : (unsigned short)0;
        ushort4* dst = (ushort4*)(ws + 131072 + (size_t)e * 8);
        dst[0] = make_ushort4(v[0], v[1], v[2], v[3]);
        dst[1] = make_ushort4(v[4], v[5], v[6], v[7]);
    }
}

// ---------------------------------------------------------------------------
// Main kernel: one WG per TWO batches (M=64 GEMMs), 256 threads = 4 waves.
// A-fragment LDS layout for 64x256 matrix M[s][c]:
//   fid = (c>>5)*4 + (s>>4); lane = ((c>>3)&3)*16 + (s&15); j = c&7
//   addr(u16) = fid*512 + lane*8 + j
// ---------------------------------------------------------------------------
__global__ __launch_bounds__(256, 2)
void svgd_kernel(const float* __restrict__ obs, const float* __restrict__ a_in,
                 const float* __restrict__ W1, const float* __restrict__ b1,
                 const float* __restrict__ W2, const float* __restrict__ b2,
                 const float* __restrict__ W3, const unsigned short* __restrict__ ws,
                 float* __restrict__ out)
{
    __shared__ __attribute__((aligned(16))) unsigned short hA[64 * NH]; // 32KB h1 / masked dh1
    __shared__ __attribute__((aligned(16))) unsigned short dA[64 * NH]; // 32KB dh2
    __shared__ __attribute__((aligned(16))) float dsp_[2 * NP * 33];    // 8.25KB dist_sq (2 batches; obs staging at init)
    __shared__ float sc_[64 * 9];       // score, stride 9
    __shared__ float Xs[64 * 9];        // X, stride 9 (2 batches)
    __shared__ float b2s[NH], W3s[NH];
    __shared__ float logp_s[64];
    __shared__ float med_s[2];

    const int t    = threadIdx.x;
    const int bb   = blockIdx.x;        // batches 2bb, 2bb+1
    const int lane = t & 63;
    const int wid  = t >> 6;
    const int w4   = wid * 4;           // this wave's first nt (GEMM N-split)
    const int quad = lane >> 4;
    const int j0 = lane * 4;            // phase-1 col group
    const int s0 = wid * 8;             // phase-1 row group (within a batch)

    const unsigned short* gW2f = ws;
    const unsigned short* gW2b = ws + 65536;
    const unsigned short* gW1p = ws + 131072;

    // ---- init: stage obs (2 batches) into dsp_, load X, zero logp ----
    const float* obs_g = obs + (size_t)bb * (2 * NP * NOBS);
    for (int p = t; p < 2 * NP * NOBS; p += 256) dsp_[p] = obs_g[p];
    const float* a_g = a_in + (size_t)bb * (2 * NP * ND);
    for (int p = t; p < 2 * NP * ND; p += 256) {
        const int s = p / 6, d = p - 6 * s;
        Xs[s * 9 + d] = a_g[p];
    }
    if (t < 64) logp_s[t] = 0.0f;
    b2s[t] = b2[t];
    W3s[t] = W3[t];

    // pair table for median (step-invariant): this lane's 8 pair offsets (i*33+j)
    int pa[8];
#pragma unroll
    for (int r = 0; r < 8; ++r) {
        const int e = lane + 64 * r;
        if (e < 496) {
            int rem = e, i0 = 0;
            while (rem >= 31 - i0) { rem -= 31 - i0; ++i0; }
            pa[r] = i0 * 33 + i0 + 1 + rem;
        } else pa[r] = -1;
    }
    __syncthreads();

    // ---- step-invariant register preloads ----
    float W1xr[ND][4];
#pragma unroll
    for (int d = 0; d < ND; ++d) {
        const float4 w = *(const float4*)(W1 + (NOBS + d) * NH + j0);
        W1xr[d][0] = w.x; W1xr[d][1] = w.y; W1xr[d][2] = w.z; W1xr[d][3] = w.w;
    }
    // c1 = obs @ W1[:17] + b1 for 16 rows (8 per batch), 4 cols
    float c1[16][4];
    {
        const float4 b1r = *(const float4*)(b1 + j0);
#pragma unroll
        for (int ss = 0; ss < 16; ++ss) {
            c1[ss][0] = b1r.x; c1[ss][1] = b1r.y; c1[ss][2] = b1r.z; c1[ss][3] = b1r.w;
        }
        for (int k = 0; k < NOBS; ++k) {
            const float4 w = *(const float4*)(W1 + k * NH + j0);
#pragma unroll
            for (int bq = 0; bq < 2; ++bq)
#pragma unroll
                for (int ss = 0; ss < 8; ++ss) {
                    const float o = dsp_[(bq * 32 + s0 + ss) * NOBS + k];
                    c1[bq * 8 + ss][0] += o * w.x; c1[bq * 8 + ss][1] += o * w.y;
                    c1[bq * 8 + ss][2] += o * w.z; c1[bq * 8 + ss][3] += o * w.w;
                }
        }
    }
    __syncthreads();  // dsp_ free now

    const f32x4 zv = {0.f, 0.f, 0.f, 0.f};

    for (int step = 0; step < NSTEPS; ++step) {
        // ---- P1: h1 = relu(c1 + X @ W1x) -> hA bf16 (A-layout), 16 rows/thread ----
#pragma unroll
        for (int bq = 0; bq < 2; ++bq)
#pragma unroll
            for (int ss = 0; ss < 8; ++ss) {
                const int s = bq * 32 + s0 + ss;
                float h0 = c1[bq * 8 + ss][0], h1v = c1[bq * 8 + ss][1];
                float h2v = c1[bq * 8 + ss][2], h3 = c1[bq * 8 + ss][3];
#pragma unroll
                for (int d = 0; d < ND; ++d) {
                    const float xv = Xs[s * 9 + d];
                    h0 += xv * W1xr[d][0]; h1v += xv * W1xr[d][1];
                    h2v += xv * W1xr[d][2]; h3 += xv * W1xr[d][3];
                }
                const int fid = (j0 >> 5) * 4 + (s >> 4);
                const int lp  = ((j0 >> 3) & 3) * 16 + (s & 15);
                *(ushort4*)&hA[fid * 512 + lp * 8 + (j0 & 7)] =
                    make_ushort4(f2bf(fmaxf(h0, 0.f)), f2bf(fmaxf(h1v, 0.f)),
                                 f2bf(fmaxf(h2v, 0.f)), f2bf(fmaxf(h3, 0.f)));
            }
        // ---- P6 (fused): dist_sq for both batches -> dsp_ ----
#pragma unroll
        for (int m = 0; m < 8; ++m) {
            const int p = t + 256 * m;
            const int qq = p >> 10, i = (p >> 5) & 31, j = p & 31;
            float s = 0.0f;
#pragma unroll
            for (int d = 0; d < ND; ++d) {
                const float df = Xs[(qq * 32 + i) * 9 + d] - Xs[(qq * 32 + j) * 9 + d];
                s += df * df;
            }
            dsp_[qq * 1056 + i * 33 + j] = s;
        }
        __syncthreads();  // S1

        // ---- P2: fwd GEMM h2_pre = h1 @ W2 (M=64) ----
        f32x4 acc[4][4];
#pragma unroll
        for (int m = 0; m < 4; ++m)
#pragma unroll
            for (int q = 0; q < 4; ++q) acc[m][q] = zv;
#pragma unroll 2
        for (int kt = 0; kt < 8; ++kt) {
            bf16x8 a[4];
#pragma unroll
            for (int m = 0; m < 4; ++m)
                a[m] = *(const bf16x8*)&hA[(kt * 4 + m) * 512 + lane * 8];
            const unsigned short* pB = gW2f + (kt * 16 + w4) * 512 + lane * 8;
#pragma unroll
            for (int q = 0; q < 4; ++q) {
                const bf16x8 bf = *(const bf16x8*)(pB + q * 512);
#pragma unroll
                for (int m = 0; m < 4; ++m) acc[m][q] = MFMA(a[m], bf, acc[m][q]);
            }
        }
        // epilogue: dh2 = (h2_pre + b2 > 0) ? W3 : 0 -> dA (A-layout)
#pragma unroll
        for (int q = 0; q < 4; ++q) {
            const int n = (w4 + q) * 16 + (lane & 15);
            const float b2v = b2s[n];
            const unsigned short w3v = f2bf(W3s[n]);
            const int colpart = (n >> 5) * 2048 + ((n >> 3) & 3) * 128 + (n & 7);
#pragma unroll
            for (int m = 0; m < 4; ++m)
#pragma unroll
                for (int reg = 0; reg < 4; ++reg) {
                    const float hp = acc[m][q][reg] + b2v;
                    dA[colpart + m * 512 + (quad * 4 + reg) * 8] =
                        (hp > 0.f) ? w3v : (unsigned short)0;
                }
        }
        __syncthreads();  // S2

        // ---- P3: bwd GEMM dh1 = dh2 @ W2^T ----
        f32x4 acc2[4][4];
#pragma unroll
        for (int m = 0; m < 4; ++m)
#pragma unroll
            for (int q = 0; q < 4; ++q) acc2[m][q] = zv;
#pragma unroll 2
        for (int kt = 0; kt < 8; ++kt) {
            bf16x8 a[4];
#pragma unroll
            for (int m = 0; m < 4; ++m)
                a[m] = *(const bf16x8*)&dA[(kt * 4 + m) * 512 + lane * 8];
            const unsigned short* pB = gW2b + (kt * 16 + w4) * 512 + lane * 8;
#pragma unroll
            for (int q = 0; q < 4; ++q) {
                const bf16x8 bf = *(const bf16x8*)(pB + q * 512);
#pragma unroll
                for (int m = 0; m < 4; ++m) acc2[m][q] = MFMA(a[m], bf, acc2[m][q]);
            }
        }
        // ---- P4: hA <- dh1 * mask, in place (wave-disjoint cols; no barrier needed) ----
#pragma unroll
        for (int q = 0; q < 4; ++q) {
            const int n = (w4 + q) * 16 + (lane & 15);
            const int colpart = (n >> 5) * 2048 + ((n >> 3) & 3) * 128 + (n & 7);
#pragma unroll
            for (int m = 0; m < 4; ++m)
#pragma unroll
                for (int reg = 0; reg < 4; ++reg) {
                    const int idx = colpart + m * 512 + (quad * 4 + reg) * 8;
                    const unsigned short hu = hA[idx];
                    hA[idx] = hu ? f2bf(acc2[m][q][reg]) : (unsigned short)0;
                }
        }
        __syncthreads();  // S3

        // ---- P5: waves 2,3: score GEMM; waves 0,1: exact median (barrier-free) ----
        if (wid >= 2) {
            const int mb = (wid - 2) * 2;
            f32x4 sa[2] = {zv, zv};
#pragma unroll
            for (int kt = 0; kt < 8; ++kt) {
                const bf16x8 bw = *(const bf16x8*)(gW1p + kt * 512 + lane * 8);
#pragma unroll
                for (int mm = 0; mm < 2; ++mm) {
                    const bf16x8 a = *(const bf16x8*)&hA[(kt * 4 + mb + mm) * 512 + lane * 8];
                    sa[mm] = MFMA(a, bw, sa[mm]);
                }
            }
            const int col = lane & 15;
            if (col < ND) {
#pragma unroll
                for (int mm = 0; mm < 2; ++mm)
#pragma unroll
                    for (int reg = 0; reg < 4; ++reg)
                        sc_[((mb + mm) * 16 + quad * 4 + reg) * 9 + col] = sa[mm][reg];
            }
        } else {
            // rank-239 of 496 pair dists == rank-511 of full 1024 multiset (exact).
            // Monotone bit-bisection on IEEE bits (positive floats: order-isomorphic).
            const float* dbase = dsp_ + wid * 1056;
            unsigned u[8];
#pragma unroll
            for (int r = 0; r < 8; ++r)
                u[r] = (pa[r] >= 0) ? __float_as_uint(dbase[pa[r]]) : 0x7f800000u;
            unsigned P = 0;
            for (int bit = 30; bit >= 0; --bit) {
                const unsigned Q = P | (1u << bit);
                int c = 0;
#pragma unroll
                for (int r = 0; r < 8; ++r)
                    c += __popcll(__ballot(u[r] < Q));
                if (c <= 239) P = Q;
            }
            if (lane == 0) med_s[wid] = __uint_as_float(P);
        }
        __syncthreads();  // S4

        // ---- stage A: phi/l4/l5 partials; thread: (batch q, particle ia, 8 j's) ----
        {
            const int q = t >> 7, rem = t & 127, ia = rem >> 2, jg = rem & 3;
            const float gam = 1.0f / (1e-8f + med_s[q] / C_LOGNP1);
            float xi[ND];
#pragma unroll
            for (int d = 0; d < ND; ++d) xi[d] = Xs[(q * 32 + ia) * 9 + d];
            float w[8] = {0, 0, 0, 0, 0, 0, 0, 0};
#pragma unroll
            for (int jj = 0; jj < 8; ++jj) {
                const int j = jg * 8 + jj;
                const float dsv = dsp_[q * 1056 + ia * 33 + j];
                const float kap = __expf(-gam * dsv);
                const float tg = 2.0f * gam * kap;
                float dot = 0.0f;
#pragma unroll
                for (int d = 0; d < ND; ++d) {
                    const float df = xi[d] - Xs[(q * 32 + j) * 9 + d];
                    const float sj = sc_[(q * 32 + j) * 9 + d];
                    w[d] += kap * sj + tg * df;   // phi numerator
                    dot += df * sj;
                }
                w[6] -= tg * dot;                 // line_4 partial
                w[7] += tg * dsv - 6.0f * kap;    // line_5 partial (pre -2*gamma)
            }
#pragma unroll
            for (int off = 1; off < 4; off <<= 1)
#pragma unroll
                for (int c = 0; c < 8; ++c) w[c] += __shfl_xor(w[c], off);
            __syncthreads();  // S5: all Xs/dsp_/sc_ reads done

            // commit (each (q,ia,d) owned by exactly one lane)
            const int base = (q * 32 + ia) * 9;
            {
                float x = Xs[base + jg] + C_LR * (w[jg] * (1.0f / 32.0f));
                Xs[base + jg] = fminf(fmaxf(x, -C_LIM), C_LIM);
            }
            if (jg < 2) {
                const int d = jg + 4;
                float x = Xs[base + d] + C_LR * (w[d] * (1.0f / 32.0f));
                Xs[base + d] = fminf(fmaxf(x, -C_LIM), C_LIM);
            }
            if (jg == 3) {
                logp_s[q * 32 + ia] -= C_LR * (w[6] * (1.0f / 32.0f)
                                               - 2.0f * gam * (w[7] * (1.0f / 32.0f)));
            }
        }
        __syncthreads();  // S6
    }

    // ---- output: a (B*N, D) then logp (B, N) ----
    for (int p = t; p < 2 * NP * ND; p += 256) {
        const int s = p / 6, d = p - 6 * s;
        out[(size_t)bb * 384 + p] = Xs[s * 9 + d];
    }
    if (t < 64) out[(size_t)NB * NP * ND + bb * 64 + t] = logp_s[t];
}

extern "C" void kernel_launch(void* const* d_in, const int* in_sizes, int n_in,
                              void* d_out, int out_size, void* d_ws, size_t ws_size,
                              hipStream_t stream) {
    const float* obs = (const float*)d_in[0];
    const float* a   = (const float*)d_in[1];
    const float* W1  = (const float*)d_in[2];
    const float* b1  = (const float*)d_in[3];
    const float* W2  = (const float*)d_in[4];
    const float* b2  = (const float*)d_in[5];
    const float* W3  = (const float*)d_in[6];
    // d_in[7] = b3: unused (constant offset drops out of grad; q-values never output)
    unsigned short* wsu = (unsigned short*)d_ws;   // needs 270336 bytes
    float* out = (float*)d_out;

    prep_swizzle<<<66, 256, 0, stream>>>(W1, W2, wsu);
    svgd_kernel<<<NB / 2, 256, 0, stream>>>(obs, a, W1, b1, W2, b2, W3, wsu, out);
}

// Round 6
// 743.060 us; speedup vs baseline: 1.7978x; 1.2502x over previous
//
#include <hip/hip_runtime.h>
#include <hip/hip_bf16.h>

#define NB 2048      // batches
#define NP 32        // particles per batch
#define ND 6         // action dim
#define NOBS 17      // obs dim
#define NH 256       // hidden
#define NSTEPS 10
#define C_LR 0.1f
#define C_LIM 1.0f
#define C_LOGNP1 3.4965075614664802f   // float32(log(33))

typedef __bf16 bf16x8 __attribute__((ext_vector_type(8)));
typedef float  f32x4  __attribute__((ext_vector_type(4)));

#define MFMA(a, b, c) __builtin_amdgcn_mfma_f32_16x16x32_bf16(a, b, c, 0, 0, 0)

// fp32 -> bf16 bits, round-to-nearest-even (finite inputs)
static __device__ __forceinline__ unsigned short f2bf(float f) {
    union { float f; unsigned u; } c; c.f = f;
    const unsigned r = c.u + 0x7fffu + ((c.u >> 16) & 1u);
    return (unsigned short)(r >> 16);
}

// ---------------------------------------------------------------------------
// Prep: B-fragment-swizzled bf16 copies in d_ws.
// Fragment (kt,nt): lane l, elem j -> B[kt*32 + (l>>4)*8 + j][nt*16 + (l&15)].
//   ws[0      ..65535]  : W2    as B (fwd)
//   ws[65536  ..131071] : W2^T  as B (bwd)
//   ws[131072 ..135167] : W1x^T (256x16, cols>=6 zero) as B (score GEMM)
//   ws[135168 ..143359] : W1aug (32x256: rows 0..22 = W1, 23..31 = 0) as B (h1 GEMM)
// ---------------------------------------------------------------------------
__global__ void prep_swizzle(const float* __restrict__ W1, const float* __restrict__ W2,
                             unsigned short* __restrict__ ws) {
    const int g = blockIdx.x * 256 + threadIdx.x;
    unsigned short v[8];
    if (g < 8192) {
        const int l = g & 63, fid = g >> 6;
        const int kt = fid >> 4, nt = fid & 15;
        const int row0 = kt * 32 + (l >> 4) * 8;
        const int col  = nt * 16 + (l & 15);
#pragma unroll
        for (int j = 0; j < 8; ++j) v[j] = f2bf(W2[(row0 + j) * NH + col]);
        ushort4* dst = (ushort4*)(ws + (size_t)g * 8);
        dst[0] = make_ushort4(v[0], v[1], v[2], v[3]);
        dst[1] = make_ushort4(v[4], v[5], v[6], v[7]);
    } else if (g < 16384) {
        const int e = g - 8192;
        const int l = e & 63, fid = e >> 6;
        const int kt = fid >> 4, nt = fid & 15;
        const int row  = nt * 16 + (l & 15);        // W2^T[k][n] = W2[n][k]
        const int col0 = kt * 32 + (l >> 4) * 8;
#pragma unroll
        for (int j = 0; j < 8; ++j) v[j] = f2bf(W2[row * NH + col0 + j]);
        ushort4* dst = (ushort4*)(ws + 65536 + (size_t)e * 8);
        dst[0] = make_ushort4(v[0], v[1], v[2], v[3]);
        dst[1] = make_ushort4(v[4], v[5], v[6], v[7]);
    } else if (g < 16896) {
        const int e = g - 16384;
        const int l = e & 63, kt = e >> 6;
        const int n  = l & 15;
        const int k0 = kt * 32 + (l >> 4) * 8;
#pragma unroll
        for (int j = 0; j < 8; ++j)
            v[j] = (n < ND) ? f2bf(W1[(NOBS + n) * NH + k0 + j]) : (unsigned short)0;
        ushort4* dst = (ushort4*)(ws + 131072 + (size_t)e * 8);
        dst[0] = make_ushort4(v[0], v[1], v[2], v[3]);
        dst[1] = make_ushort4(v[4], v[5], v[6], v[7]);
    } else if (g < 17920) {
        const int e = g - 16896;                    // 16 frags (nt) x 64 lanes
        const int l = e & 63, nt = e >> 6;
        const int col = nt * 16 + (l & 15);
        const int r0  = (l >> 4) * 8;
#pragma unroll
        for (int j = 0; j < 8; ++j)
            v[j] = (r0 + j < NOBS + ND) ? f2bf(W1[(r0 + j) * NH + col]) : (unsigned short)0;
        ushort4* dst = (ushort4*)(ws + 135168 + (size_t)e * 8);
        dst[0] = make_ushort4(v[0], v[1], v[2], v[3]);
        dst[1] = make_ushort4(v[4], v[5], v[6], v[7]);
    }
}

// ---------------------------------------------------------------------------
// Main kernel: one WG per TWO batches (M=64 GEMMs), 256 threads = 4 waves.
// A-fragment LDS layout for 64x256 matrix M[s][c]:
//   fid = (c>>5)*4 + (s>>4); addr(u16) = fid*512 + (((c>>3)&3)*16 + (s&15))*8 + (c&7)
// augA (64x32, K=32): fid = s>>4; addr = fid*512 + ((k>>3)*16 + (s&15))*8 + (k&7)
// ---------------------------------------------------------------------------
__global__ __launch_bounds__(256, 3)
void svgd_kernel(const float* __restrict__ obs, const float* __restrict__ a_in,
                 const float* __restrict__ W1, const float* __restrict__ b1,
                 const float* __restrict__ W2, const float* __restrict__ b2,
                 const float* __restrict__ W3, const unsigned short* __restrict__ ws,
                 float* __restrict__ out)
{
    __shared__ __attribute__((aligned(16))) unsigned short hA[64 * NH];   // 32KB h1 -> dh2 -> masked dh1
    __shared__ __attribute__((aligned(16))) unsigned short augA[4 * 512]; // 4KB [obs|X|0] A-frags
    __shared__ __attribute__((aligned(16))) float dsp_[2 * NP * 33];      // 8.25KB dist_sq
    __shared__ float sc_[64 * 9];       // score, stride 9
    __shared__ float Xs[64 * 9];        // X, stride 9 (2 batches)
    __shared__ float med_s[2];

    const int t    = threadIdx.x;
    const int bb   = blockIdx.x;        // batches 2bb, 2bb+1
    const int lane = t & 63;
    const int wid  = t >> 6;
    const int w4   = wid * 4;           // this wave's first nt (GEMM N-split)
    const int quad = lane >> 4;

    const unsigned short* gW2f = ws;
    const unsigned short* gW2b = ws + 65536;
    const unsigned short* gW1p = ws + 131072;
    const unsigned short* gW1f = ws + 135168;

    // ---- init: zero augA, then fill obs (bf16) and X ----
    for (int p = t; p < 2048; p += 256) augA[p] = 0;
    __syncthreads();
    const float* obs_g = obs + (size_t)bb * (2 * NP * NOBS);
    for (int p = t; p < 2 * NP * NOBS; p += 256) {
        const int s = p / NOBS, k = p - s * NOBS;
        augA[(s >> 4) * 512 + ((k >> 3) * 16 + (s & 15)) * 8 + (k & 7)] = f2bf(obs_g[p]);
    }
    const float* a_g = a_in + (size_t)bb * (2 * NP * ND);
    for (int p = t; p < 2 * NP * ND; p += 256) {
        const int s = p / 6, d = p - 6 * s;
        const float x = a_g[p];
        Xs[s * 9 + d] = x;
        augA[(s >> 4) * 512 + (32 + (s & 15)) * 8 + (d + 1)] = f2bf(x);  // k = 17+d
    }
    float logp_r = 0.0f;                // owned by (qo, iao, jgo==3)
    const int qo = t >> 7, iao = (t & 127) >> 2, jgo = t & 3;

    // step-invariant per-thread registers
    bf16x8 w1b[4];
    float b1r[4], b2r[4];
    unsigned short w3u[4];
    int colp[4];
#pragma unroll
    for (int q = 0; q < 4; ++q) {
        const int n = (w4 + q) * 16 + (lane & 15);
        w1b[q] = *(const bf16x8*)(gW1f + ((w4 + q) * 64 + lane) * 8);
        b1r[q] = b1[n]; b2r[q] = b2[n]; w3u[q] = f2bf(W3[n]);
        colp[q] = (n >> 5) * 2048 + ((n >> 3) & 3) * 128 + (n & 7);
    }
    // pair table for median: this lane's 8 pair offsets (i*33+j), i<j
    int pa[8];
#pragma unroll
    for (int r = 0; r < 8; ++r) {
        const int e = lane + 64 * r;
        if (e < 496) {
            int rem = e, i0 = 0;
            while (rem >= 31 - i0) { rem -= 31 - i0; ++i0; }
            pa[r] = i0 * 33 + i0 + 1 + rem;
        } else pa[r] = -1;
    }
    __syncthreads();

    const f32x4 zv = {0.f, 0.f, 0.f, 0.f};

    for (int step = 0; step < NSTEPS; ++step) {
        // ---- P0: h1 = relu([obs|X] @ W1aug + b1) via K=32 MFMA -> hA ----
        {
            bf16x8 a0[4];
#pragma unroll
            for (int m = 0; m < 4; ++m)
                a0[m] = *(const bf16x8*)&augA[m * 512 + lane * 8];
            f32x4 acc0[4][4];
#pragma unroll
            for (int m = 0; m < 4; ++m)
#pragma unroll
                for (int q = 0; q < 4; ++q) acc0[m][q] = MFMA(a0[m], w1b[q], zv);
#pragma unroll
            for (int q = 0; q < 4; ++q)
#pragma unroll
                for (int m = 0; m < 4; ++m)
#pragma unroll
                    for (int reg = 0; reg < 4; ++reg) {
                        const float hv = acc0[m][q][reg] + b1r[q];
                        hA[colp[q] + m * 512 + (quad * 4 + reg) * 8] =
                            (hv > 0.f) ? f2bf(hv) : (unsigned short)0;
                    }
        }
        // ---- P6 (fused): dist_sq for both batches -> dsp_ ----
#pragma unroll
        for (int m = 0; m < 8; ++m) {
            const int p = t + 256 * m;
            const int qq = p >> 10, i = (p >> 5) & 31, j = p & 31;
            float s = 0.0f;
#pragma unroll
            for (int d = 0; d < ND; ++d) {
                const float df = Xs[(qq * 32 + i) * 9 + d] - Xs[(qq * 32 + j) * 9 + d];
                s += df * df;
            }
            dsp_[qq * 1056 + i * 33 + j] = s;
        }
        __syncthreads();  // S1

        // ---- P2: fwd GEMM h2_pre = h1 @ W2 ----
        unsigned long long mask1 = 0ull;
        {
            f32x4 acc[4][4];
#pragma unroll
            for (int m = 0; m < 4; ++m)
#pragma unroll
                for (int q = 0; q < 4; ++q) acc[m][q] = zv;
#pragma unroll 2
            for (int kt = 0; kt < 8; ++kt) {
                bf16x8 a[4];
#pragma unroll
                for (int m = 0; m < 4; ++m)
                    a[m] = *(const bf16x8*)&hA[(kt * 4 + m) * 512 + lane * 8];
                const unsigned short* pB = gW2f + (kt * 16 + w4) * 512 + lane * 8;
#pragma unroll
                for (int q = 0; q < 4; ++q) {
                    const bf16x8 bf = *(const bf16x8*)(pB + q * 512);
#pragma unroll
                    for (int m = 0; m < 4; ++m) acc[m][q] = MFMA(a[m], bf, acc[m][q]);
                }
            }
            __syncthreads();  // S2: all K-loop reads of hA (h1) done
            // epilogue: snapshot h1-mask, then overwrite hA with dh2
#pragma unroll
            for (int q = 0; q < 4; ++q) {
                const float b2v = b2r[q];
                const unsigned short w3v = w3u[q];
#pragma unroll
                for (int m = 0; m < 4; ++m)
#pragma unroll
                    for (int reg = 0; reg < 4; ++reg) {
                        const int idx = colp[q] + m * 512 + (quad * 4 + reg) * 8;
                        if (hA[idx]) mask1 |= 1ull << (q * 16 + m * 4 + reg);
                        hA[idx] = (acc[m][q][reg] + b2v > 0.f) ? w3v : (unsigned short)0;
                    }
            }
        }
        __syncthreads();  // S3: dh2 visible

        // ---- P3: bwd GEMM dh1 = dh2 @ W2^T ----
        {
            f32x4 acc2[4][4];
#pragma unroll
            for (int m = 0; m < 4; ++m)
#pragma unroll
                for (int q = 0; q < 4; ++q) acc2[m][q] = zv;
#pragma unroll 2
            for (int kt = 0; kt < 8; ++kt) {
                bf16x8 a[4];
#pragma unroll
                for (int m = 0; m < 4; ++m)
                    a[m] = *(const bf16x8*)&hA[(kt * 4 + m) * 512 + lane * 8];
                const unsigned short* pB = gW2b + (kt * 16 + w4) * 512 + lane * 8;
#pragma unroll
                for (int q = 0; q < 4; ++q) {
                    const bf16x8 bf = *(const bf16x8*)(pB + q * 512);
#pragma unroll
                    for (int m = 0; m < 4; ++m) acc2[m][q] = MFMA(a[m], bf, acc2[m][q]);
                }
            }
            __syncthreads();  // S4: all K-loop reads of hA (dh2) done
            // P4: hA <- dh1 * mask (register bitmask, no hA read)
#pragma unroll
            for (int q = 0; q < 4; ++q)
#pragma unroll
                for (int m = 0; m < 4; ++m)
#pragma unroll
                    for (int reg = 0; reg < 4; ++reg) {
                        const int idx = colp[q] + m * 512 + (quad * 4 + reg) * 8;
                        hA[idx] = ((mask1 >> (q * 16 + m * 4 + reg)) & 1ull)
                                      ? f2bf(acc2[m][q][reg]) : (unsigned short)0;
                    }
        }
        __syncthreads();  // S5: masked dh1 visible

        // ---- P5: waves 2,3: score GEMM; waves 0,1: exact median (ballot bisection) ----
        if (wid >= 2) {
            const int mb = (wid - 2) * 2;
            f32x4 sa[2] = {zv, zv};
#pragma unroll
            for (int kt = 0; kt < 8; ++kt) {
                const bf16x8 bw = *(const bf16x8*)(gW1p + kt * 512 + lane * 8);
#pragma unroll
                for (int mm = 0; mm < 2; ++mm) {
                    const bf16x8 a = *(const bf16x8*)&hA[(kt * 4 + mb + mm) * 512 + lane * 8];
                    sa[mm] = MFMA(a, bw, sa[mm]);
                }
            }
            const int col = lane & 15;
            if (col < ND) {
#pragma unroll
                for (int mm = 0; mm < 2; ++mm)
#pragma unroll
                    for (int reg = 0; reg < 4; ++reg)
                        sc_[((mb + mm) * 16 + quad * 4 + reg) * 9 + col] = sa[mm][reg];
            }
        } else {
            // rank-239 of 496 pair dists == rank-511 of full 1024 multiset (exact).
            const float* dbase = dsp_ + wid * 1056;
            unsigned u[8];
#pragma unroll
            for (int r = 0; r < 8; ++r)
                u[r] = (pa[r] >= 0) ? __float_as_uint(dbase[pa[r]]) : 0x7f800000u;
            unsigned P = 0;
            for (int bit = 30; bit >= 0; --bit) {
                const unsigned Q = P | (1u << bit);
                int c = 0;
#pragma unroll
                for (int r = 0; r < 8; ++r)
                    c += __popcll(__ballot(u[r] < Q));
                if (c <= 239) P = Q;
            }
            if (lane == 0) med_s[wid] = __uint_as_float(P);
        }
        __syncthreads();  // S6

        // ---- stage A: phi/l4/l5 partials; thread (batch qo, particle iao, 8 j's) ----
        {
            const float gam = 1.0f / (1e-8f + med_s[qo] / C_LOGNP1);
            float xi[ND];
#pragma unroll
            for (int d = 0; d < ND; ++d) xi[d] = Xs[(qo * 32 + iao) * 9 + d];
            float w[8] = {0, 0, 0, 0, 0, 0, 0, 0};
#pragma unroll
            for (int jj = 0; jj < 8; ++jj) {
                const int j = jgo * 8 + jj;
                const float dsv = dsp_[qo * 1056 + iao * 33 + j];
                const float kap = __expf(-gam * dsv);
                const float tg = 2.0f * gam * kap;
                float dot = 0.0f;
#pragma unroll
                for (int d = 0; d < ND; ++d) {
                    const float df = xi[d] - Xs[(qo * 32 + j) * 9 + d];
                    const float sj = sc_[(qo * 32 + j) * 9 + d];
                    w[d] += kap * sj + tg * df;   // phi numerator
                    dot += df * sj;
                }
                w[6] -= tg * dot;                 // line_4 partial
                w[7] += tg * dsv - 6.0f * kap;    // line_5 partial (pre -2*gamma)
            }
#pragma unroll
            for (int off = 1; off < 4; off <<= 1)
#pragma unroll
                for (int c = 0; c < 8; ++c) w[c] += __shfl_xor(w[c], off);
            __syncthreads();  // S7: all Xs/dsp_/sc_ reads done

            // commit (each (q,ia,d) owned by exactly one lane); update Xs AND augA
            const int s = qo * 32 + iao;
            const int base = s * 9;
            const int abase = (s >> 4) * 512 + (32 + (s & 15)) * 8;  // k=17+d slots
            {
                float x = Xs[base + jgo] + C_LR * (w[jgo] * (1.0f / 32.0f));
                x = fminf(fmaxf(x, -C_LIM), C_LIM);
                Xs[base + jgo] = x;
                augA[abase + (jgo + 1)] = f2bf(x);
            }
            if (jgo < 2) {
                const int d = jgo + 4;
                float x = Xs[base + d] + C_LR * (w[d] * (1.0f / 32.0f));
                x = fminf(fmaxf(x, -C_LIM), C_LIM);
                Xs[base + d] = x;
                augA[abase + (d + 1)] = f2bf(x);
            }
            if (jgo == 3) {
                logp_r -= C_LR * (w[6] * (1.0f / 32.0f)
                                  - 2.0f * gam * (w[7] * (1.0f / 32.0f)));
            }
        }
        __syncthreads();  // S8
    }

    // ---- output: a (B*N, D) then logp (B, N) ----
    for (int p = t; p < 2 * NP * ND; p += 256) {
        const int s = p / 6, d = p - 6 * s;
        out[(size_t)bb * 384 + p] = Xs[s * 9 + d];
    }
    if (jgo == 3) out[(size_t)NB * NP * ND + bb * 64 + qo * 32 + iao] = logp_r;
}

extern "C" void kernel_launch(void* const* d_in, const int* in_sizes, int n_in,
                              void* d_out, int out_size, void* d_ws, size_t ws_size,
                              hipStream_t stream) {
    const float* obs = (const float*)d_in[0];
    const float* a   = (const float*)d_in[1];
    const float* W1  = (const float*)d_in[2];
    const float* b1  = (const float*)d_in[3];
    const float* W2  = (const float*)d_in[4];
    const float* b2  = (const float*)d_in[5];
    const float* W3  = (const float*)d_in[6];
    // d_in[7] = b3: unused (constant offset drops out of grad; q-values never output)
    unsigned short* wsu = (unsigned short*)d_ws;   // needs 286720 bytes
    float* out = (float*)d_out;

    prep_swizzle<<<70, 256, 0, stream>>>(W1, W2, wsu);
    svgd_kernel<<<NB / 2, 256, 0, stream>>>(obs, a, W1, b1, W2, b2, W3, wsu, out);
}

// Round 7
// 558.718 us; speedup vs baseline: 2.3909x; 1.3299x over previous
//
#include <hip/hip_runtime.h>
#include <hip/hip_bf16.h>

#define NB 2048      // batches
#define NP 32        // particles per batch
#define ND 6         // action dim
#define NOBS 17      // obs dim
#define NH 256       // hidden
#define NSTEPS 10
#define C_LR 0.1f
#define C_LIM 1.0f
#define C_LOGNP1 3.4965075614664802f   // float32(log(33))

typedef __bf16 bf16x8 __attribute__((ext_vector_type(8)));
typedef float  f32x4  __attribute__((ext_vector_type(4)));

#define MFMA(a, b, c) __builtin_amdgcn_mfma_f32_16x16x32_bf16(a, b, c, 0, 0, 0)

// fp32 -> bf16 bits, round-to-nearest-even (finite inputs)
static __device__ __forceinline__ unsigned short f2bf(float f) {
    union { float f; unsigned u; } c; c.f = f;
    const unsigned r = c.u + 0x7fffu + ((c.u >> 16) & 1u);
    return (unsigned short)(r >> 16);
}

// A/C column n -> u16 offset base within a 64-row A-layout LDS tile
static __device__ __forceinline__ int colpf(int n) {
    return ((n >> 5) << 11) + (((n >> 3) & 3) << 7) + (n & 7);
}

// ---------------------------------------------------------------------------
// Prep: B-fragment-swizzled bf16 copies in d_ws (unchanged from R6).
//   ws[0      ..65535]  : W2    as B (fwd)
//   ws[65536  ..131071] : W2^T  as B (bwd)
//   ws[131072 ..135167] : W1x^T (256x16, cols>=6 zero) as B (score GEMM)
//   ws[135168 ..143359] : W1aug (32x256: rows 0..22 = W1, 23..31 = 0) as B
// ---------------------------------------------------------------------------
__global__ void prep_swizzle(const float* __restrict__ W1, const float* __restrict__ W2,
                             unsigned short* __restrict__ ws) {
    const int g = blockIdx.x * 256 + threadIdx.x;
    unsigned short v[8];
    if (g < 8192) {
        const int l = g & 63, fid = g >> 6;
        const int kt = fid >> 4, nt = fid & 15;
        const int row0 = kt * 32 + (l >> 4) * 8;
        const int col  = nt * 16 + (l & 15);
#pragma unroll
        for (int j = 0; j < 8; ++j) v[j] = f2bf(W2[(row0 + j) * NH + col]);
        ushort4* dst = (ushort4*)(ws + (size_t)g * 8);
        dst[0] = make_ushort4(v[0], v[1], v[2], v[3]);
        dst[1] = make_ushort4(v[4], v[5], v[6], v[7]);
    } else if (g < 16384) {
        const int e = g - 8192;
        const int l = e & 63, fid = e >> 6;
        const int kt = fid >> 4, nt = fid & 15;
        const int row  = nt * 16 + (l & 15);        // W2^T[k][n] = W2[n][k]
        const int col0 = kt * 32 + (l >> 4) * 8;
#pragma unroll
        for (int j = 0; j < 8; ++j) v[j] = f2bf(W2[row * NH + col0 + j]);
        ushort4* dst = (ushort4*)(ws + 65536 + (size_t)e * 8);
        dst[0] = make_ushort4(v[0], v[1], v[2], v[3]);
        dst[1] = make_ushort4(v[4], v[5], v[6], v[7]);
    } else if (g < 16896) {
        const int e = g - 16384;
        const int l = e & 63, kt = e >> 6;
        const int n  = l & 15;
        const int k0 = kt * 32 + (l >> 4) * 8;
#pragma unroll
        for (int j = 0; j < 8; ++j)
            v[j] = (n < ND) ? f2bf(W1[(NOBS + n) * NH + k0 + j]) : (unsigned short)0;
        ushort4* dst = (ushort4*)(ws + 131072 + (size_t)e * 8);
        dst[0] = make_ushort4(v[0], v[1], v[2], v[3]);
        dst[1] = make_ushort4(v[4], v[5], v[6], v[7]);
    } else if (g < 17920) {
        const int e = g - 16896;                    // 16 frags (nt) x 64 lanes
        const int l = e & 63, nt = e >> 6;
        const int col = nt * 16 + (l & 15);
        const int r0  = (l >> 4) * 8;
#pragma unroll
        for (int j = 0; j < 8; ++j)
            v[j] = (r0 + j < NOBS + ND) ? f2bf(W1[(r0 + j) * NH + col]) : (unsigned short)0;
        ushort4* dst = (ushort4*)(ws + 135168 + (size_t)e * 8);
        dst[0] = make_ushort4(v[0], v[1], v[2], v[3]);
        dst[1] = make_ushort4(v[4], v[5], v[6], v[7]);
    }
}

// ---------------------------------------------------------------------------
// Main kernel: one WG per TWO batches (M=64 GEMMs), 256 threads = 4 waves.
// A-fragment LDS layout for 64x256 matrix M[s][c]:
//   fid = (c>>5)*4 + (s>>4); addr(u16) = fid*512 + (((c>>3)&3)*16 + (s&15))*8 + (c&7)
// All GEMMs N-split into two passes of 2 nt/wave -> 32 AGPR accumulators.
// ---------------------------------------------------------------------------
__global__ __launch_bounds__(256, 4)
void svgd_kernel(const float* __restrict__ obs, const float* __restrict__ a_in,
                 const float* __restrict__ W1, const float* __restrict__ b1,
                 const float* __restrict__ W2, const float* __restrict__ b2,
                 const float* __restrict__ W3, const unsigned short* __restrict__ ws,
                 float* __restrict__ out)
{
    __shared__ __attribute__((aligned(16))) unsigned short hA[64 * NH]; // 32KB h1 -> dh2 -> masked dh1
    __shared__ float Xs[2][576];        // 4.5KB double-buffered X, stride 9
    __shared__ float sc_[576];          // 2.25KB score, stride 9
    __shared__ float med_s[2];
    // total 39688 B -> 4 WGs/CU

    const int t    = threadIdx.x;
    const int bb   = blockIdx.x;        // batches 2bb, 2bb+1
    const int lane = t & 63;
    const int wid  = t >> 6;
    const int w4   = wid * 4;           // this wave's first nt (GEMM N-split)
    const int quad = lane >> 4;
    const int ln15 = lane & 15;
    const int qo = t >> 7, iao = (t & 127) >> 2, jgo = t & 3;

    const unsigned short* gW2f = ws;
    const unsigned short* gW2b = ws + 65536;
    const unsigned short* gW1p = ws + 131072;
    const unsigned short* gW1f = ws + 135168;

    // ---- init: obs -> hA scratch (coalesced), X -> Xs[0] ----
    {
        float* scr = (float*)hA;
        const float* obs_g = obs + (size_t)bb * 1088;
        for (int p = t; p < 1088; p += 256) scr[p] = obs_g[p];
        const float* a_g = a_in + (size_t)bb * 384;
        for (int p = t; p < 384; p += 256) {
            const int s = p / 6, d = p - 6 * s;
            Xs[0][s * 9 + d] = a_g[p];
        }
    }
    __syncthreads();
    // a0: A-fragments of [obs|X|0] (64 rows x K=32) in registers, all 4 waves
    bf16x8 a0[4];
    {
        const float* scr = (const float*)hA;
#pragma unroll
        for (int m = 0; m < 4; ++m) {
            const int s = m * 16 + ln15;
#pragma unroll
            for (int j = 0; j < 8; ++j) {
                const int k = quad * 8 + j;
                float v = 0.0f;
                if (k < NOBS) v = scr[s * NOBS + k];
                else if (k < NOBS + ND) v = Xs[0][s * 9 + (k - NOBS)];
                a0[m][j] = (__bf16)v;
            }
        }
    }
    __syncthreads();   // scr reads done before step-0 P0 writes hA

    // ---- persistent per-thread weights ----
    bf16x8 w1b[4]; float b1r[4], b2r[4]; unsigned short w3u[4];
#pragma unroll
    for (int q = 0; q < 4; ++q) {
        const int n = (w4 + q) * 16 + ln15;
        w1b[q] = *(const bf16x8*)(gW1f + ((w4 + q) * 64 + lane) * 8);
        b1r[q] = b1[n]; b2r[q] = b2[n]; w3u[q] = f2bf(W3[n]);
    }

    float logp_r = 0.0f;                // owned by jgo==3 threads
    int cur = 0;
    const f32x4 zv = {0.f, 0.f, 0.f, 0.f};

    for (int step = 0; step < NSTEPS; ++step) {
        // ---- P0: h1 = relu([obs|X] @ W1aug + b1), two N-passes, mask1 saved ----
        unsigned long long mask1 = 0ull;
#pragma unroll
        for (int p = 0; p < 2; ++p) {
            f32x4 acc0[4][2];
#pragma unroll
            for (int m = 0; m < 4; ++m)
#pragma unroll
                for (int q1 = 0; q1 < 2; ++q1)
                    acc0[m][q1] = MFMA(a0[m], w1b[2 * p + q1], zv);
#pragma unroll
            for (int q1 = 0; q1 < 2; ++q1) {
                const int q = 2 * p + q1;
                const int cp = colpf((w4 + q) * 16 + ln15);
#pragma unroll
                for (int m = 0; m < 4; ++m)
#pragma unroll
                    for (int reg = 0; reg < 4; ++reg) {
                        const float hv = acc0[m][q1][reg] + b1r[q];
                        const int idx = cp + m * 512 + (quad * 4 + reg) * 8;
                        if (hv > 0.f) {
                            mask1 |= 1ull << (q * 16 + m * 4 + reg);
                            hA[idx] = f2bf(hv);
                        } else hA[idx] = 0;
                    }
            }
        }
        __syncthreads();  // S1

        // ---- P2: fwd GEMM h2_pre = h1 @ W2, two N-passes, sign-only -> mask2 ----
        unsigned long long mask2 = 0ull;
#pragma unroll
        for (int p = 0; p < 2; ++p) {
            f32x4 acc[4][2];
#pragma unroll
            for (int m = 0; m < 4; ++m) { acc[m][0] = zv; acc[m][1] = zv; }
#pragma unroll 2
            for (int kt = 0; kt < 8; ++kt) {
                bf16x8 a[4];
#pragma unroll
                for (int m = 0; m < 4; ++m)
                    a[m] = *(const bf16x8*)&hA[(kt * 4 + m) * 512 + lane * 8];
#pragma unroll
                for (int q1 = 0; q1 < 2; ++q1) {
                    const bf16x8 bf = *(const bf16x8*)(gW2f + ((kt * 16 + w4 + 2 * p + q1) * 64 + lane) * 8);
#pragma unroll
                    for (int m = 0; m < 4; ++m) acc[m][q1] = MFMA(a[m], bf, acc[m][q1]);
                }
            }
#pragma unroll
            for (int q1 = 0; q1 < 2; ++q1)
#pragma unroll
                for (int m = 0; m < 4; ++m)
#pragma unroll
                    for (int reg = 0; reg < 4; ++reg)
                        if (acc[m][q1][reg] + b2r[2 * p + q1] > 0.f)
                            mask2 |= 1ull << ((2 * p + q1) * 16 + m * 4 + reg);
        }
        __syncthreads();  // S2: all h1 reads done
        // write dh2 = mask2 ? W3 : 0
#pragma unroll
        for (int q = 0; q < 4; ++q) {
            const int cp = colpf((w4 + q) * 16 + ln15);
#pragma unroll
            for (int m = 0; m < 4; ++m)
#pragma unroll
                for (int reg = 0; reg < 4; ++reg) {
                    const int idx = cp + m * 512 + (quad * 4 + reg) * 8;
                    hA[idx] = ((mask2 >> (q * 16 + m * 4 + reg)) & 1ull)
                                  ? w3u[q] : (unsigned short)0;
                }
        }
        __syncthreads();  // S3: dh2 visible

        // ---- P3: bwd GEMM dh1 = dh2 @ W2^T, two N-passes ----
        unsigned dh1p[16];
        f32x4 acc2[4][2];
        // pass 1 (q = 0,1) -> packed masked bf16
#pragma unroll
        for (int m = 0; m < 4; ++m) { acc2[m][0] = zv; acc2[m][1] = zv; }
#pragma unroll 2
        for (int kt = 0; kt < 8; ++kt) {
            bf16x8 a[4];
#pragma unroll
            for (int m = 0; m < 4; ++m)
                a[m] = *(const bf16x8*)&hA[(kt * 4 + m) * 512 + lane * 8];
#pragma unroll
            for (int q1 = 0; q1 < 2; ++q1) {
                const bf16x8 bf = *(const bf16x8*)(gW2b + ((kt * 16 + w4 + q1) * 64 + lane) * 8);
#pragma unroll
                for (int m = 0; m < 4; ++m) acc2[m][q1] = MFMA(a[m], bf, acc2[m][q1]);
            }
        }
#pragma unroll
        for (int q1 = 0; q1 < 2; ++q1)
#pragma unroll
            for (int m = 0; m < 4; ++m)
#pragma unroll
                for (int rp = 0; rp < 2; ++rp) {
                    const int b0 = q1 * 16 + m * 4 + rp * 2;
                    const unsigned lo = ((mask1 >> b0) & 1ull)
                        ? (unsigned)f2bf(acc2[m][q1][rp * 2]) : 0u;
                    const unsigned hi = ((mask1 >> (b0 + 1)) & 1ull)
                        ? (unsigned)f2bf(acc2[m][q1][rp * 2 + 1]) : 0u;
                    dh1p[(q1 * 4 + m) * 2 + rp] = lo | (hi << 16);
                }
        // pass 2 (q = 2,3)
#pragma unroll
        for (int m = 0; m < 4; ++m) { acc2[m][0] = zv; acc2[m][1] = zv; }
#pragma unroll 2
        for (int kt = 0; kt < 8; ++kt) {
            bf16x8 a[4];
#pragma unroll
            for (int m = 0; m < 4; ++m)
                a[m] = *(const bf16x8*)&hA[(kt * 4 + m) * 512 + lane * 8];
#pragma unroll
            for (int q1 = 0; q1 < 2; ++q1) {
                const bf16x8 bf = *(const bf16x8*)(gW2b + ((kt * 16 + w4 + 2 + q1) * 64 + lane) * 8);
#pragma unroll
                for (int m = 0; m < 4; ++m) acc2[m][q1] = MFMA(a[m], bf, acc2[m][q1]);
            }
        }
        __syncthreads();  // S4: all dh2 reads done
        // write masked dh1: pass1 from dh1p, pass2 from acc2
#pragma unroll
        for (int q1 = 0; q1 < 2; ++q1) {
            const int cp = colpf((w4 + q1) * 16 + ln15);
#pragma unroll
            for (int m = 0; m < 4; ++m)
#pragma unroll
                for (int rp = 0; rp < 2; ++rp) {
                    const unsigned v = dh1p[(q1 * 4 + m) * 2 + rp];
                    const int idx = cp + m * 512 + (quad * 4 + rp * 2) * 8;
                    hA[idx]     = (unsigned short)(v & 0xffffu);
                    hA[idx + 8] = (unsigned short)(v >> 16);
                }
        }
#pragma unroll
        for (int q1 = 0; q1 < 2; ++q1) {
            const int q = 2 + q1;
            const int cp = colpf((w4 + q) * 16 + ln15);
#pragma unroll
            for (int m = 0; m < 4; ++m)
#pragma unroll
                for (int reg = 0; reg < 4; ++reg) {
                    const int idx = cp + m * 512 + (quad * 4 + reg) * 8;
                    hA[idx] = ((mask1 >> (q * 16 + m * 4 + reg)) & 1ull)
                                  ? f2bf(acc2[m][q1][reg]) : (unsigned short)0;
                }
        }
        __syncthreads();  // S5: masked dh1 visible

        // ---- P5: waves 2,3: score GEMM; waves 0,1: exact median ----
        if (wid >= 2) {
            const int mb = (wid - 2) * 2;
            f32x4 sa[2] = {zv, zv};
#pragma unroll
            for (int kt = 0; kt < 8; ++kt) {
                const bf16x8 bw = *(const bf16x8*)(gW1p + (kt * 64 + lane) * 8);
#pragma unroll
                for (int mm = 0; mm < 2; ++mm) {
                    const bf16x8 a = *(const bf16x8*)&hA[(kt * 4 + mb + mm) * 512 + lane * 8];
                    sa[mm] = MFMA(a, bw, sa[mm]);
                }
            }
            if (ln15 < ND) {
#pragma unroll
                for (int mm = 0; mm < 2; ++mm)
#pragma unroll
                    for (int reg = 0; reg < 4; ++reg)
                        sc_[((mb + mm) * 16 + quad * 4 + reg) * 9 + ln15] = sa[mm][reg];
            }
        } else {
            // rank-239 of 496 pair dists == rank-511 of full 1024 multiset (exact).
            // Pair index closed form, dist recomputed from Xs (bitwise same as before).
            const float* Xc = &Xs[cur][wid * 288];
            unsigned u[8];
#pragma unroll
            for (int r = 0; r < 8; ++r) {
                const int e = lane + 64 * r;
                if (e < 496) {
                    int i = (int)((63.0f - sqrtf(3969.0f - 8.0f * (float)e)) * 0.5f);
                    while (i * (63 - i) / 2 > e) --i;
                    while ((i + 1) * (62 - i) / 2 <= e) ++i;
                    const int j = i + 1 + (e - i * (63 - i) / 2);
                    float s = 0.f;
#pragma unroll
                    for (int d = 0; d < ND; ++d) {
                        const float df = Xc[i * 9 + d] - Xc[j * 9 + d];
                        s += df * df;
                    }
                    u[r] = __float_as_uint(s);
                } else u[r] = 0x7f800000u;
            }
            unsigned P = 0u;
            for (int bit = 30; bit >= 0; --bit) {
                const unsigned Q = P | (1u << bit);
                int c = 0;
#pragma unroll
                for (int r = 0; r < 8; ++r)
                    c += __popcll(__ballot(u[r] < Q));
                if (c <= 239) P = Q;
            }
            if (lane == 0) med_s[wid] = __uint_as_float(P);
        }
        __syncthreads();  // S6

        // ---- phi/l4/l5 partials; thread (batch qo, particle iao, 8 j's) ----
        {
            const int nxt = cur ^ 1;
            const float gam = 1.0f / (1e-8f + med_s[qo] / C_LOGNP1);
            const float* Xc = &Xs[cur][qo * 288];
            float xi[6];
#pragma unroll
            for (int d = 0; d < ND; ++d) xi[d] = Xc[iao * 9 + d];
            float w[8] = {0, 0, 0, 0, 0, 0, 0, 0};
#pragma unroll
            for (int jj = 0; jj < 8; ++jj) {
                const int j = jgo * 8 + jj;
                float df6[6], sj6[6];
                float dsv = 0.f, dot = 0.f;
#pragma unroll
                for (int d = 0; d < ND; ++d) {
                    df6[d] = xi[d] - Xc[j * 9 + d];
                    sj6[d] = sc_[(qo * 32 + j) * 9 + d];
                    dsv += df6[d] * df6[d];
                    dot += df6[d] * sj6[d];
                }
                const float kap = __expf(-gam * dsv);
                const float tg = 2.0f * gam * kap;
#pragma unroll
                for (int d = 0; d < ND; ++d) w[d] += kap * sj6[d] + tg * df6[d];
                w[6] -= tg * dot;                 // line_4 partial
                w[7] += tg * dsv - 6.0f * kap;    // line_5 partial (pre -2*gamma)
            }
#pragma unroll
            for (int off = 1; off < 4; off <<= 1)
#pragma unroll
                for (int c = 0; c < 8; ++c) w[c] += __shfl_xor(w[c], off);
            // commit to Xs[nxt] (disjoint buffer: no barrier vs phi reads)
            const int base = (qo * 32 + iao) * 9;
            {
                float x = xi[jgo] + C_LR * (w[jgo] * (1.0f / 32.0f));
                Xs[nxt][base + jgo] = fminf(fmaxf(x, -C_LIM), C_LIM);
            }
            if (jgo < 2) {
                const int d = jgo + 4;
                float x = xi[d] + C_LR * (w[d] * (1.0f / 32.0f));
                Xs[nxt][base + d] = fminf(fmaxf(x, -C_LIM), C_LIM);
            }
            if (jgo == 3)
                logp_r -= C_LR * (w[6] * (1.0f / 32.0f)
                                  - 2.0f * gam * (w[7] * (1.0f / 32.0f)));
        }
        __syncthreads();  // S7: new Xs visible

        // refresh a0 X-slots (k=17..22 -> j=1..6, quad 2 lanes hold them)
        cur ^= 1;
        if (quad == 2) {
#pragma unroll
            for (int m = 0; m < 4; ++m) {
                const int s = m * 16 + ln15;
#pragma unroll
                for (int j = 1; j <= 6; ++j)
                    a0[m][j] = (__bf16)Xs[cur][s * 9 + (j - 1)];
            }
        }
    }

    // ---- output: a (B*N, D) then logp (B, N) ----
    for (int p = t; p < 384; p += 256) {
        const int s = p / 6, d = p - 6 * s;
        out[(size_t)bb * 384 + p] = Xs[cur][s * 9 + d];
    }
    if (jgo == 3) out[(size_t)NB * NP * ND + bb * 64 + qo * 32 + iao] = logp_r;
}

extern "C" void kernel_launch(void* const* d_in, const int* in_sizes, int n_in,
                              void* d_out, int out_size, void* d_ws, size_t ws_size,
                              hipStream_t stream) {
    const float* obs = (const float*)d_in[0];
    const float* a   = (const float*)d_in[1];
    const float* W1  = (const float*)d_in[2];
    const float* b1  = (const float*)d_in[3];
    const float* W2  = (const float*)d_in[4];
    const float* b2  = (const float*)d_in[5];
    const float* W3  = (const float*)d_in[6];
    // d_in[7] = b3: unused (constant offset drops out of grad; q-values never output)
    unsigned short* wsu = (unsigned short*)d_ws;   // needs 286720 bytes
    float* out = (float*)d_out;

    prep_swizzle<<<70, 256, 0, stream>>>(W1, W2, wsu);
    svgd_kernel<<<NB / 2, 256, 0, stream>>>(obs, a, W1, b1, W2, b2, W3, wsu, out);
}

// Round 8
// 488.539 us; speedup vs baseline: 2.7343x; 1.1436x over previous
//
#include <hip/hip_runtime.h>
#include <hip/hip_bf16.h>

#define NB 2048      // batches
#define NP 32        // particles per batch
#define ND 6         // action dim
#define NOBS 17      // obs dim
#define NH 256       // hidden
#define NSTEPS 10
#define C_LR 0.1f
#define C_LIM 1.0f
#define C_LOGNP1 3.4965075614664802f   // float32(log(33))

typedef __bf16 bf16x8 __attribute__((ext_vector_type(8)));
typedef float  f32x4  __attribute__((ext_vector_type(4)));

#define MFMA(a, b, c) __builtin_amdgcn_mfma_f32_16x16x32_bf16(a, b, c, 0, 0, 0)

// fp32 -> bf16 bits, round-to-nearest-even (finite inputs)
static __device__ __forceinline__ unsigned short f2bf(float f) {
    union { float f; unsigned u; } c; c.f = f;
    const unsigned r = c.u + 0x7fffu + ((c.u >> 16) & 1u);
    return (unsigned short)(r >> 16);
}

// A/C column n -> u16 offset base within a 64-row A-layout LDS tile
static __device__ __forceinline__ int colpf(int n) {
    return ((n >> 5) << 11) + (((n >> 3) & 3) << 7) + (n & 7);
}

// ---------------------------------------------------------------------------
// Prep: B-fragment-swizzled bf16 copies in d_ws (unchanged from R7).
//   ws[0      ..65535]  : W2    as B (fwd)
//   ws[65536  ..131071] : W2^T  as B (bwd)
//   ws[131072 ..135167] : W1x^T (256x16, cols>=6 zero) as B (score GEMM)
//   ws[135168 ..143359] : W1aug (32x256: rows 0..22 = W1, 23..31 = 0) as B
// ---------------------------------------------------------------------------
__global__ void prep_swizzle(const float* __restrict__ W1, const float* __restrict__ W2,
                             unsigned short* __restrict__ ws) {
    const int g = blockIdx.x * 256 + threadIdx.x;
    unsigned short v[8];
    if (g < 8192) {
        const int l = g & 63, fid = g >> 6;
        const int kt = fid >> 4, nt = fid & 15;
        const int row0 = kt * 32 + (l >> 4) * 8;
        const int col  = nt * 16 + (l & 15);
#pragma unroll
        for (int j = 0; j < 8; ++j) v[j] = f2bf(W2[(row0 + j) * NH + col]);
        ushort4* dst = (ushort4*)(ws + (size_t)g * 8);
        dst[0] = make_ushort4(v[0], v[1], v[2], v[3]);
        dst[1] = make_ushort4(v[4], v[5], v[6], v[7]);
    } else if (g < 16384) {
        const int e = g - 8192;
        const int l = e & 63, fid = e >> 6;
        const int kt = fid >> 4, nt = fid & 15;
        const int row  = nt * 16 + (l & 15);        // W2^T[k][n] = W2[n][k]
        const int col0 = kt * 32 + (l >> 4) * 8;
#pragma unroll
        for (int j = 0; j < 8; ++j) v[j] = f2bf(W2[row * NH + col0 + j]);
        ushort4* dst = (ushort4*)(ws + 65536 + (size_t)e * 8);
        dst[0] = make_ushort4(v[0], v[1], v[2], v[3]);
        dst[1] = make_ushort4(v[4], v[5], v[6], v[7]);
    } else if (g < 16896) {
        const int e = g - 16384;
        const int l = e & 63, kt = e >> 6;
        const int n  = l & 15;
        const int k0 = kt * 32 + (l >> 4) * 8;
#pragma unroll
        for (int j = 0; j < 8; ++j)
            v[j] = (n < ND) ? f2bf(W1[(NOBS + n) * NH + k0 + j]) : (unsigned short)0;
        ushort4* dst = (ushort4*)(ws + 131072 + (size_t)e * 8);
        dst[0] = make_ushort4(v[0], v[1], v[2], v[3]);
        dst[1] = make_ushort4(v[4], v[5], v[6], v[7]);
    } else if (g < 17920) {
        const int e = g - 16896;                    // 16 frags (nt) x 64 lanes
        const int l = e & 63, nt = e >> 6;
        const int col = nt * 16 + (l & 15);
        const int r0  = (l >> 4) * 8;
#pragma unroll
        for (int j = 0; j < 8; ++j)
            v[j] = (r0 + j < NOBS + ND) ? f2bf(W1[(r0 + j) * NH + col]) : (unsigned short)0;
        ushort4* dst = (ushort4*)(ws + 135168 + (size_t)e * 8);
        dst[0] = make_ushort4(v[0], v[1], v[2], v[3]);
        dst[1] = make_ushort4(v[4], v[5], v[6], v[7]);
    }
}

// ---------------------------------------------------------------------------
// Main kernel: one WG per TWO batches (M=64 GEMMs), 256 threads = 4 waves.
// A-fragment LDS layout for 64x256 matrix M[s][c]:
//   fid = (c>>5)*4 + (s>>4); addr(u16) = fid*512 + (((c>>3)&3)*16 + (s&15))*8 + (c&7)
// Single N-pass GEMMs: 4 nt/wave, 64 AGPR accumulators, one A-sweep per GEMM.
// ---------------------------------------------------------------------------
__global__ __launch_bounds__(256, 4)
void svgd_kernel(const float* __restrict__ obs, const float* __restrict__ a_in,
                 const float* __restrict__ W1, const float* __restrict__ b1,
                 const float* __restrict__ W2, const float* __restrict__ b2,
                 const float* __restrict__ W3, const unsigned short* __restrict__ ws,
                 float* __restrict__ out)
{
    __shared__ __attribute__((aligned(16))) unsigned short hA[64 * NH]; // 32KB h1 -> dh2 -> masked dh1
    __shared__ float Xs[2][384];        // 3KB double-buffered X, stride 6
    __shared__ float sc_[512];          // 2KB score, stride 8
    __shared__ float med_s[2];
    // total ~37.9KB -> 4 WGs/CU

    const int t    = threadIdx.x;
    const int bb   = blockIdx.x;        // batches 2bb, 2bb+1
    const int lane = t & 63;
    const int wid  = t >> 6;
    const int w4   = wid * 4;           // this wave's first nt (GEMM N-split)
    const int quad = lane >> 4;
    const int ln15 = lane & 15;
    const int qo = t >> 7, iao = (t & 127) >> 2, jgo = t & 3;

    const unsigned short* gW2f = ws;
    const unsigned short* gW2b = ws + 65536;
    const unsigned short* gW1p = ws + 131072;
    const unsigned short* gW1f = ws + 135168;

    // ---- init: obs -> hA scratch (coalesced), X -> Xs[0] ----
    {
        float* scr = (float*)hA;
        const float* obs_g = obs + (size_t)bb * 1088;
        for (int p = t; p < 1088; p += 256) scr[p] = obs_g[p];
        const float* a_g = a_in + (size_t)bb * 384;
        for (int p = t; p < 384; p += 256) Xs[0][p] = a_g[p];
    }
    __syncthreads();
    // a0: A-fragments of [obs|X|0] (64 rows x K=32) in registers, all 4 waves
    bf16x8 a0[4];
    {
        const float* scr = (const float*)hA;
#pragma unroll
        for (int m = 0; m < 4; ++m) {
            const int s = m * 16 + ln15;
#pragma unroll
            for (int j = 0; j < 8; ++j) {
                const int k = quad * 8 + j;
                float v = 0.0f;
                if (k < NOBS) v = scr[s * NOBS + k];
                else if (k < NOBS + ND) v = Xs[0][s * 6 + (k - NOBS)];
                a0[m][j] = (__bf16)v;
            }
        }
    }
    __syncthreads();   // scr reads done before step-0 P0 writes hA

    // ---- persistent per-thread scalars (no w1b: re-read from L2 each step) ----
    float b1r[4], b2r[4]; unsigned short w3u[4];
#pragma unroll
    for (int q = 0; q < 4; ++q) {
        const int n = (w4 + q) * 16 + ln15;
        b1r[q] = b1[n]; b2r[q] = b2[n]; w3u[q] = f2bf(W3[n]);
    }

    float logp_r = 0.0f;                // owned by jgo==3 threads
    int cur = 0;
    const f32x4 zv = {0.f, 0.f, 0.f, 0.f};

    for (int step = 0; step < NSTEPS; ++step) {
        // ---- P0: h1 = relu([obs|X] @ W1aug + b1), single pass, mask1 saved ----
        unsigned long long mask1 = 0ull;
        {
            bf16x8 w1B[4];
#pragma unroll
            for (int q = 0; q < 4; ++q)
                w1B[q] = *(const bf16x8*)(gW1f + ((w4 + q) * 64 + lane) * 8);
            f32x4 acc0[4][4];
#pragma unroll
            for (int m = 0; m < 4; ++m)
#pragma unroll
                for (int q = 0; q < 4; ++q) acc0[m][q] = MFMA(a0[m], w1B[q], zv);
#pragma unroll
            for (int q = 0; q < 4; ++q) {
                const int cp = colpf((w4 + q) * 16 + ln15);
#pragma unroll
                for (int m = 0; m < 4; ++m)
#pragma unroll
                    for (int reg = 0; reg < 4; ++reg) {
                        const float hv = acc0[m][q][reg] + b1r[q];
                        const int idx = cp + m * 512 + (quad * 4 + reg) * 8;
                        if (hv > 0.f) {
                            mask1 |= 1ull << (q * 16 + m * 4 + reg);
                            hA[idx] = f2bf(hv);
                        } else hA[idx] = 0;
                    }
            }
        }
        __syncthreads();  // S1

        // ---- P2: fwd GEMM h2_pre = h1 @ W2, single pass ----
        {
            f32x4 acc[4][4];
#pragma unroll
            for (int m = 0; m < 4; ++m)
#pragma unroll
                for (int q = 0; q < 4; ++q) acc[m][q] = zv;
#pragma unroll 2
            for (int kt = 0; kt < 8; ++kt) {
                bf16x8 a[4];
#pragma unroll
                for (int m = 0; m < 4; ++m)
                    a[m] = *(const bf16x8*)&hA[(kt * 4 + m) * 512 + lane * 8];
#pragma unroll
                for (int q = 0; q < 4; ++q) {
                    const bf16x8 bf = *(const bf16x8*)(gW2f + ((kt * 16 + w4 + q) * 64 + lane) * 8);
#pragma unroll
                    for (int m = 0; m < 4; ++m) acc[m][q] = MFMA(a[m], bf, acc[m][q]);
                }
            }
            __syncthreads();  // S2: all h1 reads done
            // epilogue: dh2 = (h2_pre + b2 > 0) ? W3 : 0, straight from acc
#pragma unroll
            for (int q = 0; q < 4; ++q) {
                const int cp = colpf((w4 + q) * 16 + ln15);
                const float b2v = b2r[q];
                const unsigned short w3v = w3u[q];
#pragma unroll
                for (int m = 0; m < 4; ++m)
#pragma unroll
                    for (int reg = 0; reg < 4; ++reg) {
                        const int idx = cp + m * 512 + (quad * 4 + reg) * 8;
                        hA[idx] = (acc[m][q][reg] + b2v > 0.f) ? w3v : (unsigned short)0;
                    }
            }
        }
        __syncthreads();  // S3: dh2 visible

        // ---- P3: bwd GEMM dh1 = dh2 @ W2^T, single pass ----
        {
            f32x4 acc2[4][4];
#pragma unroll
            for (int m = 0; m < 4; ++m)
#pragma unroll
                for (int q = 0; q < 4; ++q) acc2[m][q] = zv;
#pragma unroll 2
            for (int kt = 0; kt < 8; ++kt) {
                bf16x8 a[4];
#pragma unroll
                for (int m = 0; m < 4; ++m)
                    a[m] = *(const bf16x8*)&hA[(kt * 4 + m) * 512 + lane * 8];
#pragma unroll
                for (int q = 0; q < 4; ++q) {
                    const bf16x8 bf = *(const bf16x8*)(gW2b + ((kt * 16 + w4 + q) * 64 + lane) * 8);
#pragma unroll
                    for (int m = 0; m < 4; ++m) acc2[m][q] = MFMA(a[m], bf, acc2[m][q]);
                }
            }
            __syncthreads();  // S4: all dh2 reads done
            // epilogue: masked dh1 from register bitmask
#pragma unroll
            for (int q = 0; q < 4; ++q) {
                const int cp = colpf((w4 + q) * 16 + ln15);
#pragma unroll
                for (int m = 0; m < 4; ++m)
#pragma unroll
                    for (int reg = 0; reg < 4; ++reg) {
                        const int idx = cp + m * 512 + (quad * 4 + reg) * 8;
                        hA[idx] = ((mask1 >> (q * 16 + m * 4 + reg)) & 1ull)
                                      ? f2bf(acc2[m][q][reg]) : (unsigned short)0;
                    }
            }
        }
        __syncthreads();  // S5: masked dh1 visible

        // ---- P5: waves 2,3: score GEMM; waves 0,1: exact median ----
        if (wid >= 2) {
            const int mb = (wid - 2) * 2;
            f32x4 sa[2] = {zv, zv};
#pragma unroll
            for (int kt = 0; kt < 8; ++kt) {
                const bf16x8 bw = *(const bf16x8*)(gW1p + (kt * 64 + lane) * 8);
#pragma unroll
                for (int mm = 0; mm < 2; ++mm) {
                    const bf16x8 a = *(const bf16x8*)&hA[(kt * 4 + mb + mm) * 512 + lane * 8];
                    sa[mm] = MFMA(a, bw, sa[mm]);
                }
            }
            if (ln15 < ND) {
#pragma unroll
                for (int mm = 0; mm < 2; ++mm)
#pragma unroll
                    for (int reg = 0; reg < 4; ++reg)
                        sc_[((mb + mm) * 16 + quad * 4 + reg) * 8 + ln15] = sa[mm][reg];
            }
        } else {
            // rank-239 of 496 pair dists == rank-511 of full 1024 multiset (exact).
            const float* Xc = &Xs[cur][wid * 192];
            unsigned u[8];
#pragma unroll
            for (int r = 0; r < 8; ++r) {
                const int e = lane + 64 * r;
                if (e < 496) {
                    int i = (int)((63.0f - sqrtf(3969.0f - 8.0f * (float)e)) * 0.5f);
                    while (i * (63 - i) / 2 > e) --i;
                    while ((i + 1) * (62 - i) / 2 <= e) ++i;
                    const int j = i + 1 + (e - i * (63 - i) / 2);
                    float s = 0.f;
#pragma unroll
                    for (int d = 0; d < ND; ++d) {
                        const float df = Xc[i * 6 + d] - Xc[j * 6 + d];
                        s += df * df;
                    }
                    u[r] = __float_as_uint(s);
                } else u[r] = 0x7f800000u;
            }
            unsigned P = 0u;
            for (int bit = 30; bit >= 0; --bit) {
                const unsigned Q = P | (1u << bit);
                int c = 0;
#pragma unroll
                for (int r = 0; r < 8; ++r)
                    c += __popcll(__ballot(u[r] < Q));
                if (c <= 239) P = Q;
            }
            if (lane == 0) med_s[wid] = __uint_as_float(P);
        }
        __syncthreads();  // S6

        // ---- phi/l4/l5 partials; thread (batch qo, particle iao, 8 j's) ----
        {
            const int nxt = cur ^ 1;
            const float gam = 1.0f / (1e-8f + med_s[qo] / C_LOGNP1);
            const float* Xc = &Xs[cur][qo * 192];
            float xi[6];
#pragma unroll
            for (int d = 0; d < ND; ++d) xi[d] = Xc[iao * 6 + d];
            float w[8] = {0, 0, 0, 0, 0, 0, 0, 0};
#pragma unroll
            for (int jj = 0; jj < 8; ++jj) {
                const int j = jgo * 8 + jj;
                float df6[6], sj6[6];
                float dsv = 0.f, dot = 0.f;
#pragma unroll
                for (int d = 0; d < ND; ++d) {
                    df6[d] = xi[d] - Xc[j * 6 + d];
                    sj6[d] = sc_[(qo * 32 + j) * 8 + d];
                    dsv += df6[d] * df6[d];
                    dot += df6[d] * sj6[d];
                }
                const float kap = __expf(-gam * dsv);
                const float tg = 2.0f * gam * kap;
#pragma unroll
                for (int d = 0; d < ND; ++d) w[d] += kap * sj6[d] + tg * df6[d];
                w[6] -= tg * dot;                 // line_4 partial
                w[7] += tg * dsv - 6.0f * kap;    // line_5 partial (pre -2*gamma)
            }
#pragma unroll
            for (int off = 1; off < 4; off <<= 1)
#pragma unroll
                for (int c = 0; c < 8; ++c) w[c] += __shfl_xor(w[c], off);
            // commit to Xs[nxt] (disjoint buffer: no barrier vs phi reads)
            const int base = (qo * 32 + iao) * 6;
            {
                float x = xi[jgo] + C_LR * (w[jgo] * (1.0f / 32.0f));
                Xs[nxt][base + jgo] = fminf(fmaxf(x, -C_LIM), C_LIM);
            }
            if (jgo < 2) {
                const int d = jgo + 4;
                float x = xi[d] + C_LR * (w[d] * (1.0f / 32.0f));
                Xs[nxt][base + d] = fminf(fmaxf(x, -C_LIM), C_LIM);
            }
            if (jgo == 3)
                logp_r -= C_LR * (w[6] * (1.0f / 32.0f)
                                  - 2.0f * gam * (w[7] * (1.0f / 32.0f)));
        }
        __syncthreads();  // S7: new Xs visible

        // refresh a0 X-slots (k=17..22 -> j=1..6, quad 2 lanes hold them)
        cur ^= 1;
        if (quad == 2) {
#pragma unroll
            for (int m = 0; m < 4; ++m) {
                const int s = m * 16 + ln15;
#pragma unroll
                for (int j = 1; j <= 6; ++j)
                    a0[m][j] = (__bf16)Xs[cur][s * 6 + (j - 1)];
            }
        }
    }

    // ---- output: a (B*N, D) then logp (B, N) ----
    for (int p = t; p < 384; p += 256) out[(size_t)bb * 384 + p] = Xs[cur][p];
    if (jgo == 3) out[(size_t)NB * NP * ND + bb * 64 + qo * 32 + iao] = logp_r;
}

extern "C" void kernel_launch(void* const* d_in, const int* in_sizes, int n_in,
                              void* d_out, int out_size, void* d_ws, size_t ws_size,
                              hipStream_t stream) {
    const float* obs = (const float*)d_in[0];
    const float* a   = (const float*)d_in[1];
    const float* W1  = (const float*)d_in[2];
    const float* b1  = (const float*)d_in[3];
    const float* W2  = (const float*)d_in[4];
    const float* b2  = (const float*)d_in[5];
    const float* W3  = (const float*)d_in[6];
    // d_in[7] = b3: unused (constant offset drops out of grad; q-values never output)
    unsigned short* wsu = (unsigned short*)d_ws;   // needs 286720 bytes
    float* out = (float*)d_out;

    prep_swizzle<<<70, 256, 0, stream>>>(W1, W2, wsu);
    svgd_kernel<<<NB / 2, 256, 0, stream>>>(obs, a, W1, b1, W2, b2, W3, wsu, out);
}